// Round 3
// baseline (326.153 us; speedup 1.0000x reference)
//
#include <hip/hip_runtime.h>
#include <stdint.h>

typedef unsigned short u16;
typedef unsigned int   u32;
typedef __attribute__((ext_vector_type(8))) short short8;
typedef __attribute__((ext_vector_type(4))) float f32x4;

#define NTOK 4096
#define LOG2E 1.44269504088896340736f
#define QS    (0.125f * LOG2E)

// round-to-nearest-even f32 -> bf16
__device__ __forceinline__ u16 f2bf(float f) {
    u32 u = __builtin_bit_cast(u32, f);
    u += 0x7fffu + ((u >> 16) & 1u);
    return (u16)(u >> 16);
}
// pack two positive floats to bf16 pair (round-half-up; valid for exp2 outputs > 0)
__device__ __forceinline__ u32 pk_hu(float a, float b) {   // low half = a
    u32 ua = __builtin_bit_cast(u32, a) + 0x8000u;
    u32 ub = __builtin_bit_cast(u32, b) + 0x8000u;
    return (ua >> 16) | (ub & 0xffff0000u);
}

#define MFMA16x32 __builtin_amdgcn_mfma_f32_16x16x32_bf16

// ---------------- kernel 0: one-time weight convert to bf16 ----------------
// wbuf: [mat][d][c] bf16, mat: 0=wq*QS, 1=wk, 2=wv, 3=wm. grid 16 x 256.
__global__ __launch_bounds__(256) void wconv(
    const float* __restrict__ wq, const float* __restrict__ wk,
    const float* __restrict__ wv, const float* __restrict__ wm,
    u16* __restrict__ wbuf)
{
    const int mat = blockIdx.x >> 2;
    const int i   = (blockIdx.x & 3) * 1024 + threadIdx.x * 4;
    const float* src = (mat == 0) ? wq : (mat == 1) ? wk : (mat == 2) ? wv : wm;
    const float sc = (mat == 0) ? QS : 1.0f;
    const float4 v = *(const float4*)(src + i);
    uint2 pk;
    pk.x = (u32)f2bf(v.x * sc) | ((u32)f2bf(v.y * sc) << 16);
    pk.y = (u32)f2bf(v.z * sc) | ((u32)f2bf(v.w * sc) << 16);
    *(uint2*)(wbuf + mat * 4096 + i) = pk;
}

// ---------------- kernel 1: QKV projection via MFMA ----------------
// grid 512 = slab(64) x b(8, low bits for XCD affinity); block 256 = 4 waves x 16 tokens.
// x slab (64 tok x 64 ch) -> LDS bf16 [tok][ch], 16B-slot XOR swizzle (conflict-free).
// A = W-frags (b128 from wbuf, L2/L1-hot), B = X-frags from LDS.
// D: col=l15=token, row=quad*4+r (+16mt) = out channel d -> pack 4 d's into uint2 stores.
__global__ __launch_bounds__(256) void qkv_mfma2(
    const float* __restrict__ x, const u16* __restrict__ wbuf,
    const float* __restrict__ bq, const float* __restrict__ bk, const float* __restrict__ bv,
    u16* __restrict__ Q, u16* __restrict__ K, u16* __restrict__ Vt)
{
    __shared__ __align__(16) u16 Xl[64 * 64];   // [tok][ch], row 128 B, slots swizzled
    const int tid = threadIdx.x;
    const int b   = blockIdx.x & 7;
    const int n0  = (blockIdx.x >> 3) << 6;
    const int c   = tid & 63;
    const int grp = tid >> 6;

    // stage x: thread reads 4 float4 (16 tokens) of channel-row c
    const float4* xr = (const float4*)(x + ((size_t)(b * 64 + c)) * NTOK + n0);
    float4 xv[4];
#pragma unroll
    for (int k = 0; k < 4; ++k) xv[k] = xr[grp * 4 + k];
#pragma unroll
    for (int k = 0; k < 4; ++k) {
        const float vv[4] = {xv[k].x, xv[k].y, xv[k].z, xv[k].w};
#pragma unroll
        for (int e = 0; e < 4; ++e) {
            const int tok = (grp * 4 + k) * 4 + e;
            Xl[tok * 64 + (((c >> 3) ^ (tok & 7)) * 8) + (c & 7)] = f2bf(vv[e]);
        }
    }
    __syncthreads();

    const int wave = grp;
    const int lane = tid & 63;
    const int quad = lane >> 4;
    const int l15  = lane & 15;
    const int row0 = wave * 16 + l15;           // token within slab (B-frag n)

    short8 xf[2];
#pragma unroll
    for (int kk = 0; kk < 2; ++kk)
        xf[kk] = *(const short8*)&Xl[row0 * 64 + (((kk * 4 + quad) ^ (row0 & 7)) * 8)];

    const size_t tokbase = (size_t)b * NTOK + n0 + wave * 16;   // + l15 = global token
    u16* Vo = Vt + (size_t)b * 64 * NTOK;

#pragma unroll
    for (int mat = 0; mat < 3; ++mat) {
        const float* bias = (mat == 0) ? bq : (mat == 1) ? bk : bv;
        const float bsc = (mat == 0) ? QS : 1.0f;   // wq pre-scaled; scale bias to match
        short8 wf[4][2];
#pragma unroll
        for (int mt = 0; mt < 4; ++mt)
#pragma unroll
            for (int kk = 0; kk < 2; ++kk)
                wf[mt][kk] = *(const short8*)(wbuf + mat * 4096 + (mt * 16 + l15) * 64 + kk * 32 + quad * 8);
#pragma unroll
        for (int mt = 0; mt < 4; ++mt) {
            f32x4 acc = {0.f, 0.f, 0.f, 0.f};
            acc = MFMA16x32(wf[mt][0], xf[0], acc, 0, 0, 0);
            acc = MFMA16x32(wf[mt][1], xf[1], acc, 0, 0, 0);
            const float4 b4 = *(const float4*)(bias + mt * 16 + quad * 4);
            const float o0 = acc[0] + b4.x * bsc, o1 = acc[1] + b4.y * bsc;
            const float o2 = acc[2] + b4.z * bsc, o3 = acc[3] + b4.w * bsc;
            if (mat < 2) {
                uint2 pk;
                pk.x = (u32)f2bf(o0) | ((u32)f2bf(o1) << 16);
                pk.y = (u32)f2bf(o2) | ((u32)f2bf(o3) << 16);
                u16* dst = (mat == 0) ? Q : K;
                *(uint2*)(dst + (tokbase + l15) * 64 + mt * 16 + quad * 4) = pk;
            } else {
                const int d = mt * 16 + quad * 4;
                const size_t col = n0 + wave * 16 + l15;
                Vo[(size_t)(d + 0) * NTOK + col] = f2bf(o0);
                Vo[(size_t)(d + 1) * NTOK + col] = f2bf(o1);
                Vo[(size_t)(d + 2) * NTOK + col] = f2bf(o2);
                Vo[(size_t)(d + 3) * NTOK + col] = f2bf(o3);
            }
        }
    }
}

// ---------------- kernel 2: fused attention + mix + 2x2 pool ----------------
// grid 256 = oh(32) x b(8, low bits: same-b blocks share an XCD -> K/V L2-resident).
// block 512 = 8 waves, each owns a 512-token KV slice; all 128 Q-rows in regs.
// S^T = K.Q^T (consecutive D regs = consecutive tokens -> uint2 P packs).
// P buffer XOR-swizzled (16B slot ^ row&3): writes and b128 reads conflict-free.
// K/V frags prefetched one 32-token tile ahead (L2-hit latency hidden).
__global__ __launch_bounds__(512) void attn3(
    const u16* __restrict__ Q, const u16* __restrict__ K,
    const u16* __restrict__ Vt, const u16* __restrict__ wbuf,
    const float* __restrict__ bm, float* __restrict__ out)
{
    __shared__ __align__(16) char smem[65536];   // 8 waves x P[128 rows][32 tok] bf16
    const int tid  = threadIdx.x;
    const int wave = tid >> 6;
    const int lane = tid & 63;
    const int quad = lane >> 4;
    const int l15  = lane & 15;
    const int b    = blockIdx.x & 7;
    const int oh   = blockIdx.x >> 3;
    const int n0   = oh * 128;

    // Q B-frags: B[k=ch][n=Qrow]
    const u16* qbase = Q + ((size_t)(b * NTOK + n0 + l15)) * 64 + quad * 8;
    short8 qf[8][2];
#pragma unroll
    for (int nt = 0; nt < 8; ++nt)
#pragma unroll
        for (int k = 0; k < 2; ++k)
            qf[nt][k] = *(const short8*)(qbase + nt * 1024 + k * 32);

    const u16* Kb = K + ((size_t)b * NTOK + wave * 512) * 64;
    const u16* Vb = Vt + (size_t)b * 64 * NTOK + wave * 512;
    u16* Pw = (u16*)(smem + wave * 8192);        // P[row][tok]: row 64 B, swizzled slots

    f32x4 O[8][4];
#pragma unroll
    for (int mt = 0; mt < 8; ++mt)
#pragma unroll
        for (int nt = 0; nt < 4; ++nt) O[mt][nt] = (f32x4){0.f, 0.f, 0.f, 0.f};
    float lp[8] = {0.f, 0.f, 0.f, 0.f, 0.f, 0.f, 0.f, 0.f};

    short8 kf[2][2], vf[4], kf_n[2][2], vf_n[4];
    // tile-0 loads
#pragma unroll
    for (int mt = 0; mt < 2; ++mt)
#pragma unroll
        for (int kk = 0; kk < 2; ++kk)
            kf[mt][kk] = *(const short8*)(Kb + (mt * 16 + l15) * 64 + kk * 32 + quad * 8);
#pragma unroll
    for (int nt = 0; nt < 4; ++nt)
        vf[nt] = *(const short8*)(Vb + (size_t)(nt * 16 + l15) * NTOK + quad * 8);

#pragma unroll 1
    for (int t = 0; t < 16; ++t) {               // 16 tiles x 32 tokens
        // ---- S phase: S^T = K.Q^T, exp2, pack P (swizzled) ----
#pragma unroll
        for (int mt = 0; mt < 2; ++mt) {
#pragma unroll
            for (int nt = 0; nt < 8; ++nt) {
                f32x4 s = {0.f, 0.f, 0.f, 0.f};
                s = MFMA16x32(kf[mt][0], qf[nt][0], s, 0, 0, 0);
                s = MFMA16x32(kf[mt][1], qf[nt][1], s, 0, 0, 0);
                const float p0 = __builtin_amdgcn_exp2f(s[0]);
                const float p1 = __builtin_amdgcn_exp2f(s[1]);
                const float p2 = __builtin_amdgcn_exp2f(s[2]);
                const float p3 = __builtin_amdgcn_exp2f(s[3]);
                lp[nt] += (p0 + p1) + (p2 + p3);
                uint2 pk;
                pk.x = pk_hu(p0, p1);
                pk.y = pk_hu(p2, p3);
                const int slotp = (mt * 2 + (quad >> 1)) ^ (l15 & 3);
                *(uint2*)(Pw + (nt * 16 + l15) * 32 + slotp * 8 + (quad & 1) * 4) = pk;
            }
        }
        // prefetch next tile's K frags (kf just fully consumed)
        if (t < 15) {
            const u16* kt = Kb + (t + 1) * 2048;
#pragma unroll
            for (int mt = 0; mt < 2; ++mt)
#pragma unroll
                for (int kk = 0; kk < 2; ++kk)
                    kf_n[mt][kk] = *(const short8*)(kt + (mt * 16 + l15) * 64 + kk * 32 + quad * 8);
        }
        // ---- PV phase: O += P.V (A=P from own LDS; in-wave ordering, no barrier) ----
#pragma unroll
        for (int mt = 0; mt < 8; ++mt) {
            const short8 pf = *(const short8*)(Pw + (mt * 16 + l15) * 32 + ((quad ^ (l15 & 3)) * 8));
#pragma unroll
            for (int nt = 0; nt < 4; ++nt)
                O[mt][nt] = MFMA16x32(pf, vf[nt], O[mt][nt], 0, 0, 0);
        }
        // prefetch next tile's V frags
        if (t < 15) {
#pragma unroll
            for (int nt = 0; nt < 4; ++nt)
                vf_n[nt] = *(const short8*)(Vb + (size_t)(nt * 16 + l15) * NTOK + (t + 1) * 32 + quad * 8);
#pragma unroll
            for (int mt = 0; mt < 2; ++mt)
#pragma unroll
                for (int kk = 0; kk < 2; ++kk) kf[mt][kk] = kf_n[mt][kk];
#pragma unroll
            for (int nt = 0; nt < 4; ++nt) vf[nt] = vf_n[nt];
        }
    }

    // reduce lp over quads (disjoint token groups)
#pragma unroll
    for (int nt = 0; nt < 8; ++nt) {
        float s = lp[nt];
        s += __shfl_xor(s, 16);
        s += __shfl_xor(s, 32);
        lp[nt] = s;
    }

    __syncthreads();                              // all P reads done; alias region
    float* Obuf = (float*)smem;                   // [128][68] fp32 = 34816 B
    float* lbuf = (float*)(smem + 34816);         // [128] fp32
#pragma unroll
    for (int i = 0; i < 18; ++i) {
        const int idx = tid + i * 512;
        if (idx < 8832) ((float*)smem)[idx] = 0.f;
    }
    __syncthreads();

    // cross-wave O/l reduction (bank pattern: 16q+l15 -> 2-way, free)
#pragma unroll
    for (int mt = 0; mt < 8; ++mt)
#pragma unroll
        for (int nt = 0; nt < 4; ++nt)
#pragma unroll
            for (int r = 0; r < 4; ++r)
                atomicAdd(&Obuf[(mt * 16 + quad * 4 + r) * 68 + nt * 16 + l15], O[mt][nt][r]);
    if (quad == 0) {
#pragma unroll
        for (int nt = 0; nt < 8; ++nt)
            atomicAdd(&lbuf[nt * 16 + l15], lp[nt]);
    }
    __syncthreads();

    // mix = relu(O_norm . wm^T + bm); wave w -> Q-rows [16w,16w+16)
    const int arow = wave * 16 + l15;
    const float rinv = 1.0f / lbuf[arow];
    short8 af[2];
#pragma unroll
    for (int k = 0; k < 2; ++k) {
        const float* orow = &Obuf[arow * 68 + k * 32 + quad * 8];
#pragma unroll
        for (int j = 0; j < 4; ++j) {
            const float va = orow[2 * j] * rinv;
            const float vb = orow[2 * j + 1] * rinv;
            ((u32*)&af[k])[j] = (u32)f2bf(va) | ((u32)f2bf(vb) << 16);
        }
    }
    f32x4 mx[4];
#pragma unroll
    for (int nt = 0; nt < 4; ++nt) {
        const int d = nt * 16 + l15;
        const short8 w0 = *(const short8*)(wbuf + 3 * 4096 + d * 64 + quad * 8);
        const short8 w1 = *(const short8*)(wbuf + 3 * 4096 + d * 64 + 32 + quad * 8);
        f32x4 acc = {0.f, 0.f, 0.f, 0.f};
        acc = MFMA16x32(af[0], w0, acc, 0, 0, 0);
        acc = MFMA16x32(af[1], w1, acc, 0, 0, 0);
        mx[nt] = acc;
    }
#pragma unroll
    for (int nt = 0; nt < 4; ++nt) {
        const float bb = bm[nt * 16 + l15];
#pragma unroll
        for (int r = 0; r < 4; ++r) {
            float v = mx[nt][r] + bb;
            v = v > 0.f ? v : 0.f;
            Obuf[(wave * 16 + quad * 4 + r) * 68 + nt * 16 + l15] = v;
        }
    }
    __syncthreads();

    // 2x2 avg pool: rows 0..63 = image row 2oh, 64..127 = 2oh+1
    const int ow = tid & 31;
    const int cb = (tid >> 5) & 15;
#pragma unroll
    for (int i = 0; i < 4; ++i) {
        const int c = cb + i * 16;
        const float v = 0.25f * (Obuf[(2 * ow) * 68 + c] + Obuf[(2 * ow + 1) * 68 + c]
                               + Obuf[(64 + 2 * ow) * 68 + c] + Obuf[(65 + 2 * ow) * 68 + c]);
        out[((size_t)(b * 64 + c) * 32 + oh) * 32 + ow] = v;
    }
}

extern "C" void kernel_launch(void* const* d_in, const int* in_sizes, int n_in,
                              void* d_out, int out_size, void* d_ws, size_t ws_size,
                              hipStream_t stream) {
    (void)in_sizes; (void)n_in; (void)out_size; (void)ws_size;
    const float* x  = (const float*)d_in[0];
    const float* wq = (const float*)d_in[1];
    const float* bq = (const float*)d_in[2];
    const float* wk = (const float*)d_in[3];
    const float* bk = (const float*)d_in[4];
    const float* wv = (const float*)d_in[5];
    const float* bv = (const float*)d_in[6];
    const float* wm = (const float*)d_in[7];
    const float* bm = (const float*)d_in[8];

    // ws: Q bf16 [8][4096][64] | K | Vt [8][64][4096] | wbuf [4][64][64] = 12 MB + 32 KB
    u16* Q    = (u16*)d_ws;
    u16* K    = Q + (size_t)8 * NTOK * 64;
    u16* Vt   = K + (size_t)8 * NTOK * 64;
    u16* wbuf = Vt + (size_t)8 * NTOK * 64;

    wconv<<<16, 256, 0, stream>>>(wq, wk, wv, wm, wbuf);
    qkv_mfma2<<<512, 256, 0, stream>>>(x, wbuf, bq, bk, bv, Q, K, Vt);
    attn3<<<256, 512, 0, stream>>>(Q, K, Vt, wbuf, bm, (float*)d_out);
}

// Round 4
// 155.985 us; speedup vs baseline: 2.0909x; 2.0909x over previous
//
#include <hip/hip_runtime.h>
#include <stdint.h>

typedef unsigned short u16;
typedef unsigned int   u32;
typedef __attribute__((ext_vector_type(8))) short short8;
typedef __attribute__((ext_vector_type(4))) float f32x4;

#define NTOK 4096
#define LOG2E 1.44269504088896340736f
#define QS    (0.125f * LOG2E)

// round-to-nearest-even f32 -> bf16
__device__ __forceinline__ u16 f2bf(float f) {
    u32 u = __builtin_bit_cast(u32, f);
    u += 0x7fffu + ((u >> 16) & 1u);
    return (u16)(u >> 16);
}
__device__ __forceinline__ float bf2f(u16 v) {
    return __builtin_bit_cast(float, (u32)v << 16);
}
// pack two positive floats to bf16 pair (round-half-up; valid for exp2 outputs > 0)
__device__ __forceinline__ u32 pk_hu(float a, float b) {   // low half = a
    u32 ua = __builtin_bit_cast(u32, a) + 0x8000u;
    u32 ub = __builtin_bit_cast(u32, b) + 0x8000u;
    return (ua >> 16) | (ub & 0xffff0000u);
}

#define MFMA16x32 __builtin_amdgcn_mfma_f32_16x16x32_bf16

// ---------------- kernel 0: one-time weight convert to bf16 ----------------
__global__ __launch_bounds__(256) void wconv(
    const float* __restrict__ wq, const float* __restrict__ wk,
    const float* __restrict__ wv, const float* __restrict__ wm,
    u16* __restrict__ wbuf)
{
    const int mat = blockIdx.x >> 2;
    const int i   = (blockIdx.x & 3) * 1024 + threadIdx.x * 4;
    const float* src = (mat == 0) ? wq : (mat == 1) ? wk : (mat == 2) ? wv : wm;
    const float sc = (mat == 0) ? QS : 1.0f;
    const float4 v = *(const float4*)(src + i);
    uint2 pk;
    pk.x = (u32)f2bf(v.x * sc) | ((u32)f2bf(v.y * sc) << 16);
    pk.y = (u32)f2bf(v.z * sc) | ((u32)f2bf(v.w * sc) << 16);
    *(uint2*)(wbuf + mat * 4096 + i) = pk;
}

// ---------------- kernel 1: QKV projection via MFMA (unchanged from R3) ----------------
__global__ __launch_bounds__(256) void qkv_mfma2(
    const float* __restrict__ x, const u16* __restrict__ wbuf,
    const float* __restrict__ bq, const float* __restrict__ bk, const float* __restrict__ bv,
    u16* __restrict__ Q, u16* __restrict__ K, u16* __restrict__ Vt)
{
    __shared__ __align__(16) u16 Xl[64 * 64];
    const int tid = threadIdx.x;
    const int b   = blockIdx.x & 7;
    const int n0  = (blockIdx.x >> 3) << 6;
    const int c   = tid & 63;
    const int grp = tid >> 6;

    const float4* xr = (const float4*)(x + ((size_t)(b * 64 + c)) * NTOK + n0);
    float4 xv[4];
#pragma unroll
    for (int k = 0; k < 4; ++k) xv[k] = xr[grp * 4 + k];
#pragma unroll
    for (int k = 0; k < 4; ++k) {
        const float vv[4] = {xv[k].x, xv[k].y, xv[k].z, xv[k].w};
#pragma unroll
        for (int e = 0; e < 4; ++e) {
            const int tok = (grp * 4 + k) * 4 + e;
            Xl[tok * 64 + (((c >> 3) ^ (tok & 7)) * 8) + (c & 7)] = f2bf(vv[e]);
        }
    }
    __syncthreads();

    const int wave = grp;
    const int lane = tid & 63;
    const int quad = lane >> 4;
    const int l15  = lane & 15;
    const int row0 = wave * 16 + l15;

    short8 xf[2];
#pragma unroll
    for (int kk = 0; kk < 2; ++kk)
        xf[kk] = *(const short8*)&Xl[row0 * 64 + (((kk * 4 + quad) ^ (row0 & 7)) * 8)];

    const size_t tokbase = (size_t)b * NTOK + n0 + wave * 16;
    u16* Vo = Vt + (size_t)b * 64 * NTOK;

#pragma unroll
    for (int mat = 0; mat < 3; ++mat) {
        const float* bias = (mat == 0) ? bq : (mat == 1) ? bk : bv;
        const float bsc = (mat == 0) ? QS : 1.0f;
        short8 wf[4][2];
#pragma unroll
        for (int mt = 0; mt < 4; ++mt)
#pragma unroll
            for (int kk = 0; kk < 2; ++kk)
                wf[mt][kk] = *(const short8*)(wbuf + mat * 4096 + (mt * 16 + l15) * 64 + kk * 32 + quad * 8);
#pragma unroll
        for (int mt = 0; mt < 4; ++mt) {
            f32x4 acc = {0.f, 0.f, 0.f, 0.f};
            acc = MFMA16x32(wf[mt][0], xf[0], acc, 0, 0, 0);
            acc = MFMA16x32(wf[mt][1], xf[1], acc, 0, 0, 0);
            const float4 b4 = *(const float4*)(bias + mt * 16 + quad * 4);
            const float o0 = acc[0] + b4.x * bsc, o1 = acc[1] + b4.y * bsc;
            const float o2 = acc[2] + b4.z * bsc, o3 = acc[3] + b4.w * bsc;
            if (mat < 2) {
                uint2 pk;
                pk.x = (u32)f2bf(o0) | ((u32)f2bf(o1) << 16);
                pk.y = (u32)f2bf(o2) | ((u32)f2bf(o3) << 16);
                u16* dst = (mat == 0) ? Q : K;
                *(uint2*)(dst + (tokbase + l15) * 64 + mt * 16 + quad * 4) = pk;
            } else {
                const int d = mt * 16 + quad * 4;
                const size_t col = n0 + wave * 16 + l15;
                Vo[(size_t)(d + 0) * NTOK + col] = f2bf(o0);
                Vo[(size_t)(d + 1) * NTOK + col] = f2bf(o1);
                Vo[(size_t)(d + 2) * NTOK + col] = f2bf(o2);
                Vo[(size_t)(d + 3) * NTOK + col] = f2bf(o3);
            }
        }
    }
}

// ---------------- kernel 2: fused attention + mix + 2x2 pool ----------------
// grid 256 = oh(32) x b(8 low bits -> XCD affinity). block 512 = 8 waves =
// 2 Q-halves (h) x 4 KV-slices (s). Wave: 64 Q-rows (B-frags, 32 VGPR),
// 1024-token K/V slice from global (L2-resident), O = 64 AGPR. ~210 regs
// total -> NO SPILL at 2 waves/SIMD (launch_bounds(512,2) = 256-reg cap).
// LDS = exactly 64 KB: 8 slots x 8 KB. Loop: slot(w)[0:4K] = P transit
// (R3-proven swizzle). Epilogue: lp partials -> slot(4h)[4K:6K]; s!=0 waves
// write bf16 O-partials to slot(w); reducers (s==0) sum + normalize -> M0
// bf16 (swizzled) in slot(4h); all waves mix-MFMA; Mfinal fp32 [128][68]
// aliases dead slots; 2x2 pool. Plain stores + barriers, no LDS atomics.
__global__ __launch_bounds__(512, 2) void attn4(
    const u16* __restrict__ Q, const u16* __restrict__ K,
    const u16* __restrict__ Vt, const u16* __restrict__ wbuf,
    const float* __restrict__ bm, float* __restrict__ out)
{
    __shared__ __align__(16) char smem[65536];
    const int tid  = threadIdx.x;
    const int wave = tid >> 6;
    const int lane = tid & 63;
    const int quad = lane >> 4;
    const int l15  = lane & 15;
    const int h    = wave >> 2;          // Q half
    const int s    = wave & 3;           // KV slice
    const int b    = blockIdx.x & 7;
    const int oh   = blockIdx.x >> 3;
    const int n0   = oh * 128;

    // Q B-frags for my half's 64 rows: B[k=ch][n=Qrow]
    const u16* qbase = Q + ((size_t)(b * NTOK + n0 + h * 64 + l15)) * 64 + quad * 8;
    short8 qf[4][2];
#pragma unroll
    for (int nt = 0; nt < 4; ++nt)
#pragma unroll
        for (int kk = 0; kk < 2; ++kk)
            qf[nt][kk] = *(const short8*)(qbase + nt * 1024 + kk * 32);

    const u16* Kb = K + ((size_t)b * NTOK + s * 1024) * 64;
    const u16* Vb = Vt + (size_t)b * 64 * NTOK + s * 1024;
    u16* Pw = (u16*)(smem + wave * 8192);   // P[64 rows][32 tok] bf16, 4 KB

    f32x4 O[4][4];
#pragma unroll
    for (int mt = 0; mt < 4; ++mt)
#pragma unroll
        for (int nt = 0; nt < 4; ++nt) O[mt][nt] = (f32x4){0.f, 0.f, 0.f, 0.f};
    float lp[4] = {0.f, 0.f, 0.f, 0.f};

    short8 kf[2][2], vf[4], kf_n[2][2], vf_n[4];
#pragma unroll
    for (int mt = 0; mt < 2; ++mt)
#pragma unroll
        for (int kk = 0; kk < 2; ++kk)
            kf[mt][kk] = *(const short8*)(Kb + (mt * 16 + l15) * 64 + kk * 32 + quad * 8);
#pragma unroll
    for (int nt = 0; nt < 4; ++nt)
        vf[nt] = *(const short8*)(Vb + (size_t)(nt * 16 + l15) * NTOK + quad * 8);

#pragma unroll 1
    for (int t = 0; t < 32; ++t) {          // 32 tiles x 32 tokens = 1024
        // S^T = K.Q^T -> exp2 -> P (packed uint2, swizzled)
#pragma unroll
        for (int mt = 0; mt < 2; ++mt) {
#pragma unroll
            for (int nt = 0; nt < 4; ++nt) {
                f32x4 sv = {0.f, 0.f, 0.f, 0.f};
                sv = MFMA16x32(kf[mt][0], qf[nt][0], sv, 0, 0, 0);
                sv = MFMA16x32(kf[mt][1], qf[nt][1], sv, 0, 0, 0);
                const float p0 = __builtin_amdgcn_exp2f(sv[0]);
                const float p1 = __builtin_amdgcn_exp2f(sv[1]);
                const float p2 = __builtin_amdgcn_exp2f(sv[2]);
                const float p3 = __builtin_amdgcn_exp2f(sv[3]);
                lp[nt] += (p0 + p1) + (p2 + p3);
                uint2 pk;
                pk.x = pk_hu(p0, p1);
                pk.y = pk_hu(p2, p3);
                const int slotp = (mt * 2 + (quad >> 1)) ^ (l15 & 3);
                *(uint2*)(Pw + (nt * 16 + l15) * 32 + slotp * 8 + (quad & 1) * 4) = pk;
            }
        }
        if (t < 31) {
            const u16* kt = Kb + (size_t)(t + 1) * 2048;
#pragma unroll
            for (int mt = 0; mt < 2; ++mt)
#pragma unroll
                for (int kk = 0; kk < 2; ++kk)
                    kf_n[mt][kk] = *(const short8*)(kt + (mt * 16 + l15) * 64 + kk * 32 + quad * 8);
        }
        // O += P.V  (A=P own-wave LDS, B=V^T frags)
#pragma unroll
        for (int mt = 0; mt < 4; ++mt) {
            const short8 pf = *(const short8*)(Pw + (mt * 16 + l15) * 32 + ((quad ^ (l15 & 3)) * 8));
#pragma unroll
            for (int nt = 0; nt < 4; ++nt)
                O[mt][nt] = MFMA16x32(pf, vf[nt], O[mt][nt], 0, 0, 0);
        }
        if (t < 31) {
#pragma unroll
            for (int nt = 0; nt < 4; ++nt)
                vf_n[nt] = *(const short8*)(Vb + (size_t)(nt * 16 + l15) * NTOK + (t + 1) * 32 + quad * 8);
#pragma unroll
            for (int mt = 0; mt < 2; ++mt)
#pragma unroll
                for (int kk = 0; kk < 2; ++kk) kf[mt][kk] = kf_n[mt][kk];
#pragma unroll
            for (int nt = 0; nt < 4; ++nt) vf[nt] = vf_n[nt];
        }
    }

    // lp: reduce over quads (disjoint tokens) -> lane l15 holds row nt*16+l15 sum
#pragma unroll
    for (int nt = 0; nt < 4; ++nt) {
        float sum = lp[nt];
        sum += __shfl_xor(sum, 16);
        sum += __shfl_xor(sum, 32);
        lp[nt] = sum;
    }
    // lp partials (fp32, 64 per wave) -> slot(4h) + 4K + s*256 (plain stores)
    if (quad == 0) {
        float* lpw = (float*)(smem + h * 32768 + 4096 + s * 256);
#pragma unroll
        for (int nt = 0; nt < 4; ++nt) lpw[nt * 16 + l15] = lp[nt];
    }
    // O partial sections (bf16) from non-reducer waves
    if (s != 0) {
        u16* sec = (u16*)(smem + wave * 8192);
#pragma unroll
        for (int mt = 0; mt < 4; ++mt)
#pragma unroll
            for (int nt = 0; nt < 4; ++nt)
#pragma unroll
                for (int r = 0; r < 4; ++r)
                    sec[(mt * 16 + quad * 4 + r) * 64 + nt * 16 + l15] = f2bf(O[mt][nt][r]);
    }
    __syncthreads();

    if (s == 0) {
        // denominators
        float rinv[4][4];
#pragma unroll
        for (int mt = 0; mt < 4; ++mt)
#pragma unroll
            for (int r = 0; r < 4; ++r) {
                const int row = mt * 16 + quad * 4 + r;
                float sum = 0.f;
#pragma unroll
                for (int sx = 0; sx < 4; ++sx)
                    sum += *(const float*)(smem + h * 32768 + 4096 + sx * 256 + row * 4);
                rinv[mt][r] = 1.0f / sum;
            }
        // accumulate sections
#pragma unroll
        for (int sx = 1; sx < 4; ++sx) {
            const u16* sec = (const u16*)(smem + (h * 4 + sx) * 8192);
#pragma unroll
            for (int mt = 0; mt < 4; ++mt)
#pragma unroll
                for (int nt = 0; nt < 4; ++nt)
#pragma unroll
                    for (int r = 0; r < 4; ++r)
                        O[mt][nt][r] += bf2f(sec[(mt * 16 + quad * 4 + r) * 64 + nt * 16 + l15]);
        }
        // normalize -> M0 bf16 (swizzled 16B slots) into own slot(4h)
        u16* M0 = (u16*)(smem + h * 32768);
#pragma unroll
        for (int mt = 0; mt < 4; ++mt)
#pragma unroll
            for (int nt = 0; nt < 4; ++nt)
#pragma unroll
                for (int r = 0; r < 4; ++r) {
                    const int row = mt * 16 + quad * 4 + r;
                    const int ch  = nt * 16 + l15;
                    const float v = O[mt][nt][r] * rinv[mt][r];
                    M0[row * 64 + (((ch >> 3) ^ (row & 7)) * 8) + (ch & 7)] = f2bf(v);
                }
    }
    __syncthreads();

    // mix: wave w handles rows [16w, 16w+16)
    const u16* M0s = (const u16*)(smem + (wave >> 2) * 32768);
    const int rl = (wave & 3) * 16 + l15;
    const short8 af0 = *(const short8*)(M0s + rl * 64 + ((quad ^ (rl & 7)) * 8));
    const short8 af1 = *(const short8*)(M0s + rl * 64 + (((4 + quad) ^ (rl & 7)) * 8));
    short8 w0[4], w1[4];
#pragma unroll
    for (int nt = 0; nt < 4; ++nt) {
        const u16* wr = wbuf + 3 * 4096 + (nt * 16 + l15) * 64;
        w0[nt] = *(const short8*)(wr + quad * 8);
        w1[nt] = *(const short8*)(wr + 32 + quad * 8);
    }
    float bias[4];
#pragma unroll
    for (int nt = 0; nt < 4; ++nt) bias[nt] = bm[nt * 16 + l15];
    __syncthreads();                     // af reads complete before Mfinal aliases slots

    float* Mf = (float*)smem;            // [128][68] fp32 = 34816 B
#pragma unroll
    for (int nt = 0; nt < 4; ++nt) {
        f32x4 acc = {0.f, 0.f, 0.f, 0.f};
        acc = MFMA16x32(af0, w0[nt], acc, 0, 0, 0);
        acc = MFMA16x32(af1, w1[nt], acc, 0, 0, 0);
#pragma unroll
        for (int r = 0; r < 4; ++r) {
            float v = acc[r] + bias[nt];
            v = v > 0.f ? v : 0.f;
            Mf[(wave * 16 + quad * 4 + r) * 68 + nt * 16 + l15] = v;
        }
    }
    __syncthreads();

    // 2x2 avg pool (bilinear 2x, half-pixel): rows 0..63 = image row 2oh, 64..127 = 2oh+1
    const int ow = tid & 31;
    const int cb = (tid >> 5) & 15;
#pragma unroll
    for (int i = 0; i < 4; ++i) {
        const int c = cb + i * 16;
        const float v = 0.25f * (Mf[(2 * ow) * 68 + c] + Mf[(2 * ow + 1) * 68 + c]
                               + Mf[(64 + 2 * ow) * 68 + c] + Mf[(65 + 2 * ow) * 68 + c]);
        out[((size_t)(b * 64 + c) * 32 + oh) * 32 + ow] = v;
    }
}

extern "C" void kernel_launch(void* const* d_in, const int* in_sizes, int n_in,
                              void* d_out, int out_size, void* d_ws, size_t ws_size,
                              hipStream_t stream) {
    (void)in_sizes; (void)n_in; (void)out_size; (void)ws_size;
    const float* x  = (const float*)d_in[0];
    const float* wq = (const float*)d_in[1];
    const float* bq = (const float*)d_in[2];
    const float* wk = (const float*)d_in[3];
    const float* bk = (const float*)d_in[4];
    const float* wv = (const float*)d_in[5];
    const float* bv = (const float*)d_in[6];
    const float* wm = (const float*)d_in[7];
    const float* bm = (const float*)d_in[8];

    // ws: Q bf16 [8][4096][64] | K | Vt [8][64][4096] | wbuf [4][64][64] = 12 MB + 32 KB
    u16* Q    = (u16*)d_ws;
    u16* K    = Q + (size_t)8 * NTOK * 64;
    u16* Vt   = K + (size_t)8 * NTOK * 64;
    u16* wbuf = Vt + (size_t)8 * NTOK * 64;

    wconv<<<16, 256, 0, stream>>>(wq, wk, wv, wm, wbuf);
    qkv_mfma2<<<512, 256, 0, stream>>>(x, wbuf, bq, bk, bv, Q, K, Vt);
    attn4<<<256, 512, 0, stream>>>(Q, K, Vt, wbuf, bm, (float*)d_out);
}